// Round 3
// baseline (536.260 us; speedup 1.0000x reference)
//
#include <hip/hip_runtime.h>

// ---------------------------------------------------------------------------
// Kagome 3x3 conv, B=2048, Cin=Cout=128, 16x16 spatial, fp32 in/out.
// R3: 32x32x16 fp16 MFMA + explicit A-ring-3 / B-ring-2 software pipeline.
// R2 diagnosis: latency-bound (MfmaUtil 31%, VGPR 56 -> no prefetch depth;
// per-kstep 4 L2 loads ~250cyc unhidden). 32x32 tiles halve per-kstep operand
// regs (2A+2B frags), freeing budget for explicit rings within the 128-reg /
// 2-blocks-per-CU envelope. acc stays 64 regs (4x f32x16).
// One block = one image; x in LDS [pos][ci] fp16, XOR slot swizzle; W
// pre-expanded fragment-major fp16 in d_ws; BC via 18x18 LDS map.
// ---------------------------------------------------------------------------

typedef _Float16 f16x8 __attribute__((ext_vector_type(8)));
typedef float    f32x16 __attribute__((ext_vector_type(16)));
typedef unsigned short u16x8 __attribute__((ext_vector_type(8)));

#define ROW_BYTES      256          // 128 ci * 2B fp16 per position row
#define ZERO_ROW       256
#define MASK_OFF       65792        // 257*256
#define BIAS_OFF       66816
#define MAP_OFF        67328
#define SMEM_BYTES     67976        // 2 blocks/CU

// Boundary-condition pairs packed (dr<<24)|(dc<<16)|(sr<<8)|sc  (padded 18x18)
#define BCP(a,b,c,d) ((unsigned)((a)<<24)|((b)<<16)|((c)<<8)|(d))
__constant__ unsigned int BC_PAIRS[37] = {
    BCP(1,3,13,15),  BCP(1,5,13,5),   BCP(2,7,14,7),   BCP(3,9,15,9),
    BCP(4,10,16,10), BCP(4,11,16,11), BCP(6,13,6,1),   BCP(7,13,7,1),
    BCP(8,14,8,2),   BCP(10,15,10,3), BCP(11,15,11,3), BCP(12,16,12,4),
    BCP(14,15,2,3),  BCP(14,16,2,4),  BCP(15,15,3,3),  BCP(16,14,4,2),
    BCP(17,13,5,1),  BCP(17,11,5,11), BCP(16,9,4,9),   BCP(15,7,3,7),
    BCP(14,6,2,6),   BCP(14,5,2,5),   BCP(12,3,12,15), BCP(10,2,10,14),
    BCP(8,1,8,13),   BCP(6,0,6,12),   BCP(4,0,16,12),  BCP(4,1,16,13),
    BCP(3,1,15,13),  BCP(2,2,14,14),  BCP(5,0,5,12),   BCP(9,2,9,14),
    BCP(13,4,1,4),   BCP(15,8,3,8),   BCP(17,12,5,12), BCP(15,14,3,2),
    BCP(13,16,1,4)
};

// direct transcription of _make_mask zero rules
__device__ __forceinline__ bool mask_zero(int r, int c) {
    bool z = false;
    z |= (r < 8 && c >= 8 + r);
    z |= (r >= 9 && c <= r - 9);
    z |= (r == 0 && c >= 4 && c < 8);
    z |= (r == 1 && c >= 6 && c < 9);
    z |= (r == 2 && (c == 8 || c == 9));
    z |= (r == 3 && (c == 9 || c == 10));
    z |= (r == 5 && c == 12);
    z |= (r == 6 && (c == 12 || c == 13));
    z |= (r == 7 && (c == 13 || c == 14));
    z |= (r == 8 && (c == 14 || c == 15));
    z |= (r == 9 && (c == 14 || c == 15));
    z |= (r == 10 && (c == 14 || c == 15));
    z |= (r == 11 && c == 15);
    z |= (r == 12 && c == 15);
    z |= (r >= 13 && c >= 14);
    z |= (r == 14 && c == 13);
    z |= (r == 15 && c == 13);
    z |= (r == 15 && (c == 7 || c == 8));
    z |= (r == 13 && c == 5);
    z |= (r == 14 && (c == 6 || c == 7));
    z |= (r == 8 && (c == 0 || c == 1));
    z |= (r == 9 && c == 1);
    z |= (r == 7 && c == 0);
    z |= (r == 3 && c == 0);
    z |= (r <= 2 && c == 0);
    z |= (r <= 1 && c <= 1);
    z |= (r == 0 && c == 2);
    return z;
}

// ---------------------------------------------------------------------------
// Prep: expand W (OIHW fp32) into 32x32x16-fragment-major fp16 in d_ws.
// g <-> (it 0..71, ct32 0..3, lane, j):  g = ((it*4+ct)*64 + l)*8 + j
//   it = tap*8 + ks;  co = ct*32 + (l&31);  ci = ks*16 + ((l>>5)&1)*8 + j
// A-frag (32x32x16: row=l&31, k=(l>>5)*8+j) load: wf + (it*4+ct)*1024 + l*16.
// ---------------------------------------------------------------------------
__global__ void kag_prep_w(const float* __restrict__ W, _Float16* __restrict__ wf) {
    int g  = blockIdx.x * 256 + threadIdx.x;   // grid covers exactly 147456
    int j  = g & 7;
    int l  = (g >> 3) & 63;
    int ct = (g >> 9) & 3;
    int it = g >> 11;                           // 0..71
    int tap = it >> 3;
    int ks  = it & 7;
    int co = ct * 32 + (l & 31);
    int ci = ks * 16 + ((l >> 5) & 1) * 8 + j;
    wf[g] = (_Float16)W[(co * 128 + ci) * 9 + tap];
}

#define MFMA32(A, B, C) __builtin_amdgcn_mfma_f32_32x32x16_f16(A, B, C, 0, 0, 0)

// one pipeline step: 4 MFMAs on slot (S3,S2), prefetch A(it+3)->S3, B(it+2)->S2
#define STEP(LOC, S3, S2, RB0, RB1) do {                                        \
    acc00 = MFMA32(A##S3##c0, B##S2##p0, acc00);                                \
    acc01 = MFMA32(A##S3##c0, B##S2##p1, acc01);                                \
    acc10 = MFMA32(A##S3##c1, B##S2##p0, acc10);                                \
    acc11 = MFMA32(A##S3##c1, B##S2##p1, acc11);                                \
    { int it3_ = t3*8 + (LOC) + 3; it3_ = it3_ > 71 ? 71 : it3_;                \
      const char* pw_ = wb + it3_ * 4096;                                       \
      A##S3##c0 = *(const f16x8*)pw_;                                           \
      A##S3##c1 = *(const f16x8*)(pw_ + 1024); }                                \
    { const int ks2_ = ((LOC) + 2) & 7;                                         \
      B##S2##p0 = *(const f16x8*)(smem + (RB0) +                                \
          ((((ks2_ * 2) + half) ^ (((RB0) >> 8) & 15)) << 4));                  \
      B##S2##p1 = *(const f16x8*)(smem + (RB1) +                                \
          ((((ks2_ * 2) + half) ^ (((RB1) >> 8) & 15)) << 4)); }                \
} while (0)

// map lookup for tap: rb = srow*256 (rxs derived as (rb>>8)&15)
#define LOADMAP(TAP, R0, R1) do {                                               \
    int t_ = (TAP); t_ = t_ > 8 ? 8 : t_;                                       \
    int kh_ = (t_ * 11) >> 5; int kw_ = t_ - kh_ * 3;                           \
    R0 = ((int)mp[(prow0 + kh_) * 18 + pcol + kw_]) << 8;                       \
    R1 = ((int)mp[(prow1 + kh_) * 18 + pcol + kw_]) << 8;                       \
} while (0)

__global__ __launch_bounds__(512, 4) void kag_main(
    const float* __restrict__ x, const float* __restrict__ bias,
    const _Float16* __restrict__ wf, float* __restrict__ out)
{
    extern __shared__ char smem[];
    const int tid = threadIdx.x;
    const int b   = blockIdx.x;
    const float* xb = x + (size_t)b * 32768;

    // ---------------- phase 0: x -> LDS [pos][ci] fp16, swizzled -----------
    {
        int p       = tid & 255;
        int halfsel = tid >> 8;
        int px      = p & 15;
        char* rowbase = smem + p * ROW_BYTES;
        #pragma unroll
        for (int g = 0; g < 8; ++g) {
            int ci0 = halfsel * 64 + g * 8;
            f16x8 hv;
            #pragma unroll
            for (int j = 0; j < 8; ++j)
                hv[j] = (_Float16)xb[(size_t)(ci0 + j) * 256 + p];
            int slot = (ci0 >> 3) ^ px;
            *(f16x8*)(rowbase + (slot << 4)) = hv;
        }
    }
    if (tid < 16) {
        u16x8 z = (u16x8)0;
        *(u16x8*)(smem + ZERO_ROW * ROW_BYTES + tid * 16) = z;
    }
    if (tid < 256) {
        int r = tid >> 4, c = tid & 15;
        ((float*)(smem + MASK_OFF))[tid] = mask_zero(r, c) ? 0.0f : 1.0f;
    }
    if (tid < 128) ((float*)(smem + BIAS_OFF))[tid] = bias[tid];
    for (int i = tid; i < 324; i += 512) {
        int r = i / 18, c = i - r * 18;
        unsigned short v = ZERO_ROW;
        if (r >= 1 && r <= 16 && c >= 1 && c <= 16) v = (unsigned short)((r - 1) * 16 + (c - 1));
        ((unsigned short*)(smem + MAP_OFF))[i] = v;
    }
    __syncthreads();
    if (tid < 37) {
        unsigned v = BC_PAIRS[tid];
        int dr = v >> 24, dc = (v >> 16) & 255, sr = (v >> 8) & 255, sc = v & 255;
        ((unsigned short*)(smem + MAP_OFF))[dr * 18 + dc] =
            (unsigned short)((sr - 1) * 16 + (sc - 1));
    }
    __syncthreads();

    // ---------------- main GEMM loop (32x32x16, ring-pipelined) ------------
    const int lane = tid & 63;
    const int w    = tid >> 6;
    const int l31  = lane & 31;
    const int half = lane >> 5;                  // k-half within fragment
    const int pt32base = (w & 3) * 2;            // 2 pos-tiles32 per wave
    const int ct32base = (w >> 2) * 2;           // 2 co-tiles32 per wave

    const int prow0 = (pt32base + 0) * 2 + (l31 >> 4);  // image row of lane's pos
    const int prow1 = (pt32base + 1) * 2 + (l31 >> 4);
    const int pcol  = lane & 15;

    const unsigned short* mp = (const unsigned short*)(smem + MAP_OFF);
    const char* wb = (const char*)wf + ct32base * 1024 + lane * 16;

    f32x16 acc00 = (f32x16)0.0f, acc01 = (f32x16)0.0f;
    f32x16 acc10 = (f32x16)0.0f, acc11 = (f32x16)0.0f;

    int m0rb0, m0rb1, m1rb0, m1rb1, m2rb0, m2rb1, m3rb0, m3rb1;
    LOADMAP(0, m0rb0, m0rb1);

    // prologue: A for it=0,1,2 ; B for it=0,1 (tap 0)
    f16x8 A0c0 = *(const f16x8*)(wb);
    f16x8 A0c1 = *(const f16x8*)(wb + 1024);
    f16x8 A1c0 = *(const f16x8*)(wb + 4096);
    f16x8 A1c1 = *(const f16x8*)(wb + 4096 + 1024);
    f16x8 A2c0 = *(const f16x8*)(wb + 8192);
    f16x8 A2c1 = *(const f16x8*)(wb + 8192 + 1024);
    f16x8 B0p0 = *(const f16x8*)(smem + m0rb0 + (((0 + half) ^ ((m0rb0 >> 8) & 15)) << 4));
    f16x8 B0p1 = *(const f16x8*)(smem + m0rb1 + (((0 + half) ^ ((m0rb1 >> 8) & 15)) << 4));
    f16x8 B1p0 = *(const f16x8*)(smem + m0rb0 + (((2 + half) ^ ((m0rb0 >> 8) & 15)) << 4));
    f16x8 B1p1 = *(const f16x8*)(smem + m0rb1 + (((2 + half) ^ ((m0rb1 >> 8) & 15)) << 4));

    for (int t3 = 0; t3 < 9; t3 += 3) {          // 3 super-taps of 24 k-steps
        LOADMAP(t3 + 1, m1rb0, m1rb1);
        STEP( 0, 0, 0, m0rb0, m0rb1);  STEP( 1, 1, 1, m0rb0, m0rb1);
        STEP( 2, 2, 0, m0rb0, m0rb1);  STEP( 3, 0, 1, m0rb0, m0rb1);
        STEP( 4, 1, 0, m0rb0, m0rb1);  STEP( 5, 2, 1, m0rb0, m0rb1);
        STEP( 6, 0, 0, m1rb0, m1rb1);  STEP( 7, 1, 1, m1rb0, m1rb1);
        STEP( 8, 2, 0, m1rb0, m1rb1);  STEP( 9, 0, 1, m1rb0, m1rb1);
        STEP(10, 1, 0, m1rb0, m1rb1);  STEP(11, 2, 1, m1rb0, m1rb1);
        LOADMAP(t3 + 2, m2rb0, m2rb1);
        STEP(12, 0, 0, m1rb0, m1rb1);  STEP(13, 1, 1, m1rb0, m1rb1);
        STEP(14, 2, 0, m2rb0, m2rb1);  STEP(15, 0, 1, m2rb0, m2rb1);
        STEP(16, 1, 0, m2rb0, m2rb1);  STEP(17, 2, 1, m2rb0, m2rb1);
        STEP(18, 0, 0, m2rb0, m2rb1);  STEP(19, 1, 1, m2rb0, m2rb1);
        LOADMAP(t3 + 3, m3rb0, m3rb1);
        STEP(20, 2, 0, m2rb0, m2rb1);  STEP(21, 0, 1, m2rb0, m2rb1);
        STEP(22, 1, 0, m3rb0, m3rb1);  STEP(23, 2, 1, m3rb0, m3rb1);
        m0rb0 = m3rb0; m0rb1 = m3rb1;
    }

    // ---------------- epilogue: bias + mask + store ------------------------
    const float* mk = (const float*)(smem + MASK_OFF);
    const float* bs = (const float*)(smem + BIAS_OFF);
    float* outb = out + (size_t)b * 32768;

    // C/D 32x32: col(pos) = lane&31, row(co) = (reg&3) + 8*(reg>>2) + 4*(lane>>5)
#define STORE(ACC, C2, P2) do {                                                 \
        int pos_ = (pt32base + (P2)) * 32 + l31;                                \
        float m_ = mk[pos_];                                                    \
        int cb_  = (ct32base + (C2)) * 32 + 4 * half;                           \
        _Pragma("unroll")                                                       \
        for (int r_ = 0; r_ < 16; ++r_) {                                       \
            int co_ = cb_ + (r_ & 3) + 8 * (r_ >> 2);                           \
            outb[(size_t)co_ * 256 + pos_] = (ACC[r_] + bs[co_]) * m_;          \
        }                                                                       \
    } while (0)

    STORE(acc00, 0, 0);
    STORE(acc01, 0, 1);
    STORE(acc10, 1, 0);
    STORE(acc11, 1, 1);
#undef STORE
}

extern "C" void kernel_launch(void* const* d_in, const int* in_sizes, int n_in,
                              void* d_out, int out_size, void* d_ws, size_t ws_size,
                              hipStream_t stream) {
    const float* x    = (const float*)d_in[0];
    const float* W    = (const float*)d_in[1];
    const float* bias = (const float*)d_in[2];
    float* out = (float*)d_out;
    _Float16* wf = (_Float16*)d_ws;              // needs 294912 B

    hipFuncSetAttribute((const void*)kag_main,
                        hipFuncAttributeMaxDynamicSharedMemorySize, SMEM_BYTES);

    kag_prep_w<<<576, 256, 0, stream>>>(W, wf);            // 576*256 == 147456
    kag_main<<<2048, 512, SMEM_BYTES, stream>>>(x, bias, wf, out);
}